// Round 8
// baseline (222.921 us; speedup 1.0000x reference)
//
#include <hip/hip_runtime.h>
#include <hip/hip_bf16.h>

// Shapes: x:(16,32,128) mask:(16,128) w1:(256,66) b1:(256) w2:(128,256) b2:(128) pool_w:(128,21)
// L=128, L2=16384, dim=256, out_c=128. Output (16,128) f32.

#define NB 16
#define CIN 33
#define DIM 256
#define LEN 128
#define OC 128
#define L2 16384

typedef short bf16x8 __attribute__((ext_vector_type(8)));
typedef float f32x4 __attribute__((ext_vector_type(4)));

__device__ __forceinline__ unsigned short f32_to_bf16_rne(float f) {
    unsigned u = __float_as_uint(f);
    unsigned rb = ((u >> 16) & 1u) + 0x7FFFu;
    return (unsigned short)((u + rb) >> 16);
}
__device__ __forceinline__ float bf16_to_f32(unsigned short b) {
    return __uint_as_float(((unsigned)b) << 16);
}

// ---------------- kernel A: ha/hb = w1a/w1b @ xm, with b1 folded in (half each) ----------------
__global__ __launch_bounds__(128) void kA(const float* __restrict__ x,
                                          const float* __restrict__ mask,
                                          const float* __restrict__ w1,
                                          const float* __restrict__ b1,
                                          float* __restrict__ ha,
                                          float* __restrict__ hb) {
    int d = blockIdx.x;
    int n = blockIdx.y;
    int l = threadIdx.x;
    const float* w1r = w1 + d * (2 * CIN);
    float a = 0.f, b = 0.f;
#pragma unroll
    for (int c = 0; c < CIN; ++c) {
        float xv = (c < 32) ? x[((size_t)n * 32 + c) * LEN + l] : mask[(size_t)n * LEN + l];
        a = fmaf(w1r[c], xv, a);
        b = fmaf(w1r[CIN + c], xv, b);
    }
    float hb1 = 0.5f * b1[d];
    ha[((size_t)n * DIM + d) * LEN + l] = a + hb1;
    hb[((size_t)n * DIM + d) * LEN + l] = b + hb1;
}

// ---------------- kernel W: split w2 into bf16 hi/lo ----------------
__global__ __launch_bounds__(256) void kW(const float* __restrict__ w2,
                                          unsigned short* __restrict__ w2hi,
                                          unsigned short* __restrict__ w2lo) {
    int idx = blockIdx.x * 256 + threadIdx.x;   // 32768 total
    float v = w2[idx];
    unsigned short h = f32_to_bf16_rne(v);
    unsigned short l = f32_to_bf16_rne(v - bf16_to_f32(h));
    w2hi[idx] = h;
    w2lo[idx] = l;
}

// ---------------- kernel B: MFMA split-bf16 GEMM ----------------
#define ROWP 40
__global__ __launch_bounds__(256) void kB(const float* __restrict__ ha,
                                          const float* __restrict__ hb,
                                          const unsigned short* __restrict__ w2hi,
                                          const unsigned short* __restrict__ w2lo,
                                          const float* __restrict__ b2,
                                          unsigned short* __restrict__ y,
                                          int nbase) {
    __shared__ unsigned short Wh[128 * ROWP], Wl[128 * ROWP];
    __shared__ unsigned short Bh[128 * ROWP], Bl[128 * ROWP];
    __shared__ float ha_s[DIM];
    int i0 = blockIdx.x;
    int zloc = blockIdx.y;
    int n = nbase + zloc;
    int tid = threadIdx.x;
    int wv = tid >> 6, l = tid & 63;
    int g = l >> 4, lr = l & 15;

    if (tid < DIM) ha_s[tid] = ha[((size_t)n * DIM + tid) * LEN + i0];

    f32x4 acc[2][8];
    float bv2[2][4];
#pragma unroll
    for (int mt = 0; mt < 2; ++mt)
#pragma unroll
        for (int r = 0; r < 4; ++r)
            bv2[mt][r] = b2[(wv * 2 + mt) * 16 + g * 4 + r];
#pragma unroll
    for (int mt = 0; mt < 2; ++mt)
#pragma unroll
        for (int nt = 0; nt < 8; ++nt)
#pragma unroll
            for (int r = 0; r < 4; ++r)
                acc[mt][nt][r] = bv2[mt][r];

    __syncthreads();

    for (int d0 = 0; d0 < DIM; d0 += 32) {
        {
            int o = tid & 127, hf2 = tid >> 7;
            const unsigned short* gh = w2hi + (size_t)o * DIM + d0 + hf2 * 16;
            const unsigned short* gl = w2lo + (size_t)o * DIM + d0 + hf2 * 16;
            uint4 a0 = *(const uint4*)&gh[0], a1 = *(const uint4*)&gh[8];
            uint4 c0 = *(const uint4*)&gl[0], c1 = *(const uint4*)&gl[8];
            *(uint4*)&Wh[o * ROWP + hf2 * 16] = a0;
            *(uint4*)&Wh[o * ROWP + hf2 * 16 + 8] = a1;
            *(uint4*)&Wl[o * ROWP + hf2 * 16] = c0;
            *(uint4*)&Wl[o * ROWP + hf2 * 16 + 8] = c1;
        }
        {
            int j = tid & 127, kh = tid >> 7;
            union { unsigned short u[16]; uint4 q[2]; } hiv, lov;
#pragma unroll
            for (int kk = 0; kk < 16; ++kk) {
                int d = d0 + kh * 16 + kk;
                float hv = fmaxf(ha_s[d] + hb[((size_t)n * DIM + d) * LEN + j], 0.f);
                unsigned short hbits = f32_to_bf16_rne(hv);
                unsigned short lbits = f32_to_bf16_rne(hv - bf16_to_f32(hbits));
                hiv.u[kk] = hbits;
                lov.u[kk] = lbits;
            }
            *(uint4*)&Bh[j * ROWP + kh * 16] = hiv.q[0];
            *(uint4*)&Bh[j * ROWP + kh * 16 + 8] = hiv.q[1];
            *(uint4*)&Bl[j * ROWP + kh * 16] = lov.q[0];
            *(uint4*)&Bl[j * ROWP + kh * 16 + 8] = lov.q[1];
        }
        __syncthreads();

        bf16x8 ah[2], al[2];
#pragma unroll
        for (int mt = 0; mt < 2; ++mt) {
            int rowi = (wv * 2 + mt) * 16 + lr;
            ah[mt] = *(bf16x8*)&Wh[rowi * ROWP + g * 8];
            al[mt] = *(bf16x8*)&Wl[rowi * ROWP + g * 8];
        }
#pragma unroll
        for (int nt = 0; nt < 8; ++nt) {
            int brow = nt * 16 + lr;
            bf16x8 bh = *(bf16x8*)&Bh[brow * ROWP + g * 8];
            bf16x8 bl = *(bf16x8*)&Bl[brow * ROWP + g * 8];
#pragma unroll
            for (int mt = 0; mt < 2; ++mt) {
                acc[mt][nt] = __builtin_amdgcn_mfma_f32_16x16x32_bf16(ah[mt], bh, acc[mt][nt], 0, 0, 0);
                acc[mt][nt] = __builtin_amdgcn_mfma_f32_16x16x32_bf16(ah[mt], bl, acc[mt][nt], 0, 0, 0);
                acc[mt][nt] = __builtin_amdgcn_mfma_f32_16x16x32_bf16(al[mt], bh, acc[mt][nt], 0, 0, 0);
            }
        }
        __syncthreads();
    }

#pragma unroll
    for (int mt = 0; mt < 2; ++mt)
#pragma unroll
        for (int nt = 0; nt < 8; ++nt)
#pragma unroll
            for (int r = 0; r < 4; ++r) {
                int o = (wv * 2 + mt) * 16 + g * 4 + r;
                int col = nt * 16 + lr;
                y[((size_t)zloc * OC + o) * L2 + (size_t)i0 * LEN + col] =
                    f32_to_bf16_rne(acc[mt][nt][r]);
            }
}

// ---------------- kernel C: rank-slot histogram pooling (single atomic pass) ----------------
// 32768 bins (ordified bf16 >> 1), u16 counts packed 2/word = 16384 words = 64 KB dynamic LDS.
// Phase 1: histogram via packed LDS atomics; SAVE each element's returned intra-bin offset.
// Phase 2: hierarchical scan -> per-bin descending-rank start = L2 - P_incl(bin), written back.
// Phase 3: plain ds_read of start (same-address reads broadcast -> no atomic serialization),
// slot r = start + saved offset, apply the reference's exact per-element f32 weight formula.
__global__ __launch_bounds__(1024) void kC(const unsigned short* __restrict__ y,
                                           const float* __restrict__ pw,
                                           float* __restrict__ out,
                                           int nbase) {
    extern __shared__ unsigned hist[];   // 16384 words = 64 KB
    int row = blockIdx.x;
    int och = row & (OC - 1);
    int n = nbase + (row >> 7);
    int t = threadIdx.x;
    int lane = t & 63, wv = t >> 6;
    const unsigned short* yr = y + (size_t)row * L2;
    const float* pwo = pw + och * 21;

    // 1. zero hist: thread owns words [t*16, t*16+16)
#pragma unroll
    for (int q = 0; q < 4; ++q)
        *(uint4*)&hist[t * 16 + q * 4] = make_uint4(0, 0, 0, 0);
    __syncthreads();

    // 2. load 16 bf16, histogram; save intra-bin offsets from the atomic returns.
    union { uint4 q[2]; unsigned short u[16]; } ld;
    ld.q[0] = *(const uint4*)&yr[t * 16];
    ld.q[1] = *(const uint4*)&yr[t * 16 + 8];
    unsigned off16[8];
#pragma unroll
    for (int e = 0; e < 16; ++e) {
        unsigned u = ld.u[e];
        unsigned k16 = u ^ ((u & 0x8000u) ? 0xFFFFu : 0x8000u);
        unsigned hi = (k16 >> 1) & 1;
        unsigned old = atomicAdd(&hist[k16 >> 2], hi ? 0x10000u : 1u);
        unsigned myoff = hi ? (old >> 16) : (old & 0xFFFFu);
        if (e & 1) off16[e >> 1] |= myoff << 16;
        else       off16[e >> 1] = myoff;
    }
    __syncthreads();

    // 3. scan: thread owns words [t*16, t*16+16) = bins [t*32, t*32+32), ascending
    unsigned wreg[16];
#pragma unroll
    for (int q = 0; q < 4; ++q) {
        uint4 v4 = *(const uint4*)&hist[t * 16 + q * 4];
        wreg[q * 4 + 0] = v4.x; wreg[q * 4 + 1] = v4.y;
        wreg[q * 4 + 2] = v4.z; wreg[q * 4 + 3] = v4.w;
    }
    int Ti = 0;
#pragma unroll
    for (int q = 0; q < 16; ++q)
        Ti += (int)(wreg[q] & 0xFFFFu) + (int)(wreg[q] >> 16);
    int incl = Ti;
#pragma unroll
    for (int d = 1; d < 64; d <<= 1) {
        int u2 = __shfl_up(incl, d, 64);
        if (lane >= d) incl += u2;
    }
    __syncthreads();                       // all wreg reads complete -> hist is scratch
    if (lane == 63) hist[t * 16] = (unsigned)incl;   // stash wave totals
    __syncthreads();
    int base = 0;
#pragma unroll
    for (int k = 0; k < 16; ++k) {
        int tw = (int)hist[(k * 64 + 63) * 16];      // broadcast read
        base += (k < wv) ? tw : 0;
    }
    __syncthreads();                       // totals consumed; owners may overwrite
    int P = base + (incl - Ti);            // ascending exclusive prefix before this thread's bins

    // write back per-bin descending-rank starts: start(b) = L2 - P_incl(b)
#pragma unroll
    for (int q = 0; q < 16; ++q) {
        int clo = (int)(wreg[q] & 0xFFFFu), chi = (int)(wreg[q] >> 16);
        P += clo;
        unsigned slo = (unsigned)(L2 - P);
        P += chi;
        unsigned shi = (unsigned)(L2 - P);
        wreg[q] = slo | (shi << 16);
    }
#pragma unroll
    for (int q = 0; q < 4; ++q)
        *(uint4*)&hist[t * 16 + q * 4] =
            make_uint4(wreg[q * 4 + 0], wreg[q * 4 + 1], wreg[q * 4 + 2], wreg[q * 4 + 3]);
    __syncthreads();

    // 4. per-element: plain read of bin start, slot = start + saved offset, weight, fma
    float acc = 0.f;
#pragma unroll
    for (int e = 0; e < 16; ++e) {
        unsigned u = ld.u[e];
        unsigned k16 = u ^ ((u & 0x8000u) ? 0xFFFFu : 0x8000u);
        unsigned hi = (k16 >> 1) & 1;
        unsigned w = hist[k16 >> 2];
        unsigned start = hi ? (w >> 16) : (w & 0xFFFFu);
        unsigned myoff = (e & 1) ? (off16[e >> 1] >> 16) : (off16[e >> 1] & 0xFFFFu);
        int r = (int)(start + myoff);
        float posf = fminf((float)r / 16383.0f, 1.0f);
        float idxf = 20.0f * posf;
        int idx = (int)idxf;
        float frac = idxf - (float)idx;
        int i1 = min(idx + 1, 20);
        float wvw = (1.0f - frac) * pwo[idx] + frac * pwo[i1];
        float val = __uint_as_float(((unsigned)u) << 16);
        acc = fmaf(val, wvw, acc);
    }

    // 5. reduce (hist free after reads; barrier-protected reuse)
#pragma unroll
    for (int d = 32; d >= 1; d >>= 1) acc += __shfl_xor(acc, d, 64);
    __syncthreads();
    if (lane == 0) ((float*)hist)[wv] = acc;
    __syncthreads();
    if (t == 0) {
        double tot = 0.0;
#pragma unroll
        for (int k = 0; k < 16; ++k) tot += (double)((const float*)hist)[k];
        out[(size_t)n * OC + och] = (float)(tot * (1.0 / (double)L2));
    }
}

extern "C" void kernel_launch(void* const* d_in, const int* in_sizes, int n_in,
                              void* d_out, int out_size, void* d_ws, size_t ws_size,
                              hipStream_t stream) {
    const float* x    = (const float*)d_in[0];
    const float* mask = (const float*)d_in[1];
    const float* w1   = (const float*)d_in[2];
    const float* b1   = (const float*)d_in[3];
    const float* w2   = (const float*)d_in[4];
    const float* b2   = (const float*)d_in[5];
    const float* pw   = (const float*)d_in[6];
    float* out = (float*)d_out;

    char* ws = (char*)d_ws;
    float* ha = (float*)ws;                                       // 2 MB
    float* hb = ha + (size_t)NB * DIM * LEN;                      // 2 MB
    unsigned short* w2hi = (unsigned short*)(ws + (size_t)2 * NB * DIM * LEN * 4);  // 64 KB
    unsigned short* w2lo = w2hi + (size_t)OC * DIM;                                  // 64 KB
    unsigned short* y = w2lo + (size_t)OC * DIM;                  // up to 64 MB bf16

    size_t used = (size_t)2 * NB * DIM * LEN * 4 + (size_t)2 * OC * DIM * 2;
    size_t perN = (size_t)OC * L2 * 2;   // 4 MB per n (bf16)
    int nchunk = 1;
    if (ws_size > used + perN) {
        size_t c = (ws_size - used) / perN;
        nchunk = (int)(c > NB ? NB : c);
    }

    hipLaunchKernelGGL(kA, dim3(DIM, NB), dim3(128), 0, stream, x, mask, w1, b1, ha, hb);
    hipLaunchKernelGGL(kW, dim3(OC * DIM / 256), dim3(256), 0, stream, w2, w2hi, w2lo);
    for (int base = 0; base < NB; base += nchunk) {
        int nc = nchunk < (NB - base) ? nchunk : (NB - base);
        hipLaunchKernelGGL(kB, dim3(LEN, nc), dim3(256), 0, stream, ha, hb, w2hi, w2lo, b2, y, base);
        hipLaunchKernelGGL(kC, dim3(OC * nc), dim3(1024), 65536, stream, y, pw, out, base);
    }
}

// Round 9
// 195.771 us; speedup vs baseline: 1.1387x; 1.1387x over previous
//
#include <hip/hip_runtime.h>
#include <hip/hip_bf16.h>

// Shapes: x:(16,32,128) mask:(16,128) w1:(256,66) b1:(256) w2:(128,256) b2:(128) pool_w:(128,21)
// L=128, L2=16384, dim=256, out_c=128. Output (16,128) f32.

#define NB 16
#define CIN 33
#define DIM 256
#define LEN 128
#define OC 128
#define L2 16384

typedef short bf16x8 __attribute__((ext_vector_type(8)));
typedef float f32x4 __attribute__((ext_vector_type(4)));

__device__ __forceinline__ unsigned short f32_to_bf16_rne(float f) {
    unsigned u = __float_as_uint(f);
    unsigned rb = ((u >> 16) & 1u) + 0x7FFFu;
    return (unsigned short)((u + rb) >> 16);
}
__device__ __forceinline__ float bf16_to_f32(unsigned short b) {
    return __uint_as_float(((unsigned)b) << 16);
}

// ---------------- kernel A: ha/hb = w1a/w1b @ xm, with b1 folded in (half each) ----------------
__global__ __launch_bounds__(128) void kA(const float* __restrict__ x,
                                          const float* __restrict__ mask,
                                          const float* __restrict__ w1,
                                          const float* __restrict__ b1,
                                          float* __restrict__ ha,
                                          float* __restrict__ hb) {
    int d = blockIdx.x;
    int n = blockIdx.y;
    int l = threadIdx.x;
    const float* w1r = w1 + d * (2 * CIN);
    float a = 0.f, b = 0.f;
#pragma unroll
    for (int c = 0; c < CIN; ++c) {
        float xv = (c < 32) ? x[((size_t)n * 32 + c) * LEN + l] : mask[(size_t)n * LEN + l];
        a = fmaf(w1r[c], xv, a);
        b = fmaf(w1r[CIN + c], xv, b);
    }
    float hb1 = 0.5f * b1[d];
    ha[((size_t)n * DIM + d) * LEN + l] = a + hb1;
    hb[((size_t)n * DIM + d) * LEN + l] = b + hb1;
}

// ---------------- kernel W: split w2 into bf16 hi/lo ----------------
__global__ __launch_bounds__(256) void kW(const float* __restrict__ w2,
                                          unsigned short* __restrict__ w2hi,
                                          unsigned short* __restrict__ w2lo) {
    int idx = blockIdx.x * 256 + threadIdx.x;   // 32768 total
    float v = w2[idx];
    unsigned short h = f32_to_bf16_rne(v);
    unsigned short l = f32_to_bf16_rne(v - bf16_to_f32(h));
    w2hi[idx] = h;
    w2lo[idx] = l;
}

// ---------------- kernel B: MFMA split-bf16 GEMM ----------------
#define ROWP 40
__global__ __launch_bounds__(256) void kB(const float* __restrict__ ha,
                                          const float* __restrict__ hb,
                                          const unsigned short* __restrict__ w2hi,
                                          const unsigned short* __restrict__ w2lo,
                                          const float* __restrict__ b2,
                                          unsigned short* __restrict__ y,
                                          int nbase) {
    __shared__ unsigned short Wh[128 * ROWP], Wl[128 * ROWP];
    __shared__ unsigned short Bh[128 * ROWP], Bl[128 * ROWP];
    __shared__ float ha_s[DIM];
    int i0 = blockIdx.x;
    int zloc = blockIdx.y;
    int n = nbase + zloc;
    int tid = threadIdx.x;
    int wv = tid >> 6, l = tid & 63;
    int g = l >> 4, lr = l & 15;

    if (tid < DIM) ha_s[tid] = ha[((size_t)n * DIM + tid) * LEN + i0];

    f32x4 acc[2][8];
    float bv2[2][4];
#pragma unroll
    for (int mt = 0; mt < 2; ++mt)
#pragma unroll
        for (int r = 0; r < 4; ++r)
            bv2[mt][r] = b2[(wv * 2 + mt) * 16 + g * 4 + r];
#pragma unroll
    for (int mt = 0; mt < 2; ++mt)
#pragma unroll
        for (int nt = 0; nt < 8; ++nt)
#pragma unroll
            for (int r = 0; r < 4; ++r)
                acc[mt][nt][r] = bv2[mt][r];

    __syncthreads();

    for (int d0 = 0; d0 < DIM; d0 += 32) {
        {
            int o = tid & 127, hf2 = tid >> 7;
            const unsigned short* gh = w2hi + (size_t)o * DIM + d0 + hf2 * 16;
            const unsigned short* gl = w2lo + (size_t)o * DIM + d0 + hf2 * 16;
            uint4 a0 = *(const uint4*)&gh[0], a1 = *(const uint4*)&gh[8];
            uint4 c0 = *(const uint4*)&gl[0], c1 = *(const uint4*)&gl[8];
            *(uint4*)&Wh[o * ROWP + hf2 * 16] = a0;
            *(uint4*)&Wh[o * ROWP + hf2 * 16 + 8] = a1;
            *(uint4*)&Wl[o * ROWP + hf2 * 16] = c0;
            *(uint4*)&Wl[o * ROWP + hf2 * 16 + 8] = c1;
        }
        {
            int j = tid & 127, kh = tid >> 7;
            union { unsigned short u[16]; uint4 q[2]; } hiv, lov;
#pragma unroll
            for (int kk = 0; kk < 16; ++kk) {
                int d = d0 + kh * 16 + kk;
                float hv = fmaxf(ha_s[d] + hb[((size_t)n * DIM + d) * LEN + j], 0.f);
                unsigned short hbits = f32_to_bf16_rne(hv);
                unsigned short lbits = f32_to_bf16_rne(hv - bf16_to_f32(hbits));
                hiv.u[kk] = hbits;
                lov.u[kk] = lbits;
            }
            *(uint4*)&Bh[j * ROWP + kh * 16] = hiv.q[0];
            *(uint4*)&Bh[j * ROWP + kh * 16 + 8] = hiv.q[1];
            *(uint4*)&Bl[j * ROWP + kh * 16] = lov.q[0];
            *(uint4*)&Bl[j * ROWP + kh * 16 + 8] = lov.q[1];
        }
        __syncthreads();

        bf16x8 ah[2], al[2];
#pragma unroll
        for (int mt = 0; mt < 2; ++mt) {
            int rowi = (wv * 2 + mt) * 16 + lr;
            ah[mt] = *(bf16x8*)&Wh[rowi * ROWP + g * 8];
            al[mt] = *(bf16x8*)&Wl[rowi * ROWP + g * 8];
        }
#pragma unroll
        for (int nt = 0; nt < 8; ++nt) {
            int brow = nt * 16 + lr;
            bf16x8 bh = *(bf16x8*)&Bh[brow * ROWP + g * 8];
            bf16x8 bl = *(bf16x8*)&Bl[brow * ROWP + g * 8];
#pragma unroll
            for (int mt = 0; mt < 2; ++mt) {
                acc[mt][nt] = __builtin_amdgcn_mfma_f32_16x16x32_bf16(ah[mt], bh, acc[mt][nt], 0, 0, 0);
                acc[mt][nt] = __builtin_amdgcn_mfma_f32_16x16x32_bf16(ah[mt], bl, acc[mt][nt], 0, 0, 0);
                acc[mt][nt] = __builtin_amdgcn_mfma_f32_16x16x32_bf16(al[mt], bh, acc[mt][nt], 0, 0, 0);
            }
        }
        __syncthreads();
    }

#pragma unroll
    for (int mt = 0; mt < 2; ++mt)
#pragma unroll
        for (int nt = 0; nt < 8; ++nt)
#pragma unroll
            for (int r = 0; r < 4; ++r) {
                int o = (wv * 2 + mt) * 16 + g * 4 + r;
                int col = nt * 16 + lr;
                y[((size_t)zloc * OC + o) * L2 + (size_t)i0 * LEN + col] =
                    f32_to_bf16_rne(acc[mt][nt][r]);
            }
}

// ---------------- kernel C: rank-slot histogram pooling (swizzled, single atomic pass) ---------
// Physical word layout XOR-swizzled: swz(w) = w ^ ((w>>2)&0xC). This permutes the 4 quads
// within each thread's 16-word block so structured b128 accesses (addr = t*64, banks {0-3,16-19})
// become conflict-free; scattered accesses pay one extra XOR. Bijection; identity for w<16.
__device__ __forceinline__ unsigned swz(unsigned w) { return w ^ ((w >> 2) & 0xCu); }

__global__ __launch_bounds__(1024, 8) void kC(const unsigned short* __restrict__ y,
                                              const float* __restrict__ pw,
                                              float* __restrict__ out,
                                              int nbase) {
    extern __shared__ unsigned hist[];   // 16384 words = 64 KB
    int row = blockIdx.x;
    int och = row & (OC - 1);
    int n = nbase + (row >> 7);
    int t = threadIdx.x;
    int lane = t & 63, wv = t >> 6;
    const unsigned short* yr = y + (size_t)row * L2;
    const float* pwo = pw + och * 21;
    int tsw = (t & 3) << 2;              // quad swizzle offset for this thread's block

    // 1. zero hist: thread owns words [t*16, t*16+16), write quads in swizzled order
#pragma unroll
    for (int q = 0; q < 4; ++q)
        *(uint4*)&hist[t * 16 + ((q << 2) ^ tsw)] = make_uint4(0, 0, 0, 0);
    __syncthreads();

    // 2. load 16 bf16, histogram (swizzled word); save intra-bin offsets from atomic returns.
    union { uint4 q[2]; unsigned short u[16]; } ld;
    ld.q[0] = *(const uint4*)&yr[t * 16];
    ld.q[1] = *(const uint4*)&yr[t * 16 + 8];
    unsigned off16[8];
#pragma unroll
    for (int e = 0; e < 16; ++e) {
        unsigned u = ld.u[e];
        unsigned k16 = u ^ ((u & 0x8000u) ? 0xFFFFu : 0x8000u);
        unsigned hi = (k16 >> 1) & 1;
        unsigned old = atomicAdd(&hist[swz(k16 >> 2)], hi ? 0x10000u : 1u);
        unsigned myoff = hi ? (old >> 16) : (old & 0xFFFFu);
        if (e & 1) off16[e >> 1] |= myoff << 16;
        else       off16[e >> 1] = myoff;
    }
    __syncthreads();

    // 3. scan: thread owns logical words [t*16, t*16+16) = bins [t*32, t*32+32), ascending
    unsigned wreg[16];
#pragma unroll
    for (int q = 0; q < 4; ++q) {
        uint4 v4 = *(const uint4*)&hist[t * 16 + ((q << 2) ^ tsw)];
        wreg[q * 4 + 0] = v4.x; wreg[q * 4 + 1] = v4.y;
        wreg[q * 4 + 2] = v4.z; wreg[q * 4 + 3] = v4.w;
    }
    int Ti = 0;
#pragma unroll
    for (int q = 0; q < 16; ++q)
        Ti += (int)(wreg[q] & 0xFFFFu) + (int)(wreg[q] >> 16);
    int incl = Ti;
#pragma unroll
    for (int d = 1; d < 64; d <<= 1) {
        int u2 = __shfl_up(incl, d, 64);
        if (lane >= d) incl += u2;
    }
    __syncthreads();                       // all wreg reads complete -> hist is scratch
    if (lane == 63) hist[swz(t * 16)] = (unsigned)incl;   // stash wave totals (own block)
    __syncthreads();
    int base = 0;
#pragma unroll
    for (int k = 0; k < 16; ++k) {
        int tw = (int)hist[swz((k * 64 + 63) * 16)];      // broadcast read
        base += (k < wv) ? tw : 0;
    }
    __syncthreads();                       // totals consumed; owners may overwrite
    int P = base + (incl - Ti);            // ascending exclusive prefix before this thread's bins

    // write back per-bin descending-rank starts: start(b) = L2 - P_incl(b)
#pragma unroll
    for (int q = 0; q < 16; ++q) {
        int clo = (int)(wreg[q] & 0xFFFFu), chi = (int)(wreg[q] >> 16);
        P += clo;
        unsigned slo = (unsigned)(L2 - P);
        P += chi;
        unsigned shi = (unsigned)(L2 - P);
        wreg[q] = slo | (shi << 16);
    }
#pragma unroll
    for (int q = 0; q < 4; ++q)
        *(uint4*)&hist[t * 16 + ((q << 2) ^ tsw)] =
            make_uint4(wreg[q * 4 + 0], wreg[q * 4 + 1], wreg[q * 4 + 2], wreg[q * 4 + 3]);
    __syncthreads();

    // 4. per-element: plain read of bin start (same-word reads broadcast), slot = start + offset
    float acc = 0.f;
#pragma unroll
    for (int e = 0; e < 16; ++e) {
        unsigned u = ld.u[e];
        unsigned k16 = u ^ ((u & 0x8000u) ? 0xFFFFu : 0x8000u);
        unsigned hi = (k16 >> 1) & 1;
        unsigned w = hist[swz(k16 >> 2)];
        unsigned start = hi ? (w >> 16) : (w & 0xFFFFu);
        unsigned myoff = (e & 1) ? (off16[e >> 1] >> 16) : (off16[e >> 1] & 0xFFFFu);
        int r = (int)(start + myoff);
        float posf = fminf((float)r / 16383.0f, 1.0f);
        float idxf = 20.0f * posf;
        int idx = (int)idxf;
        float frac = idxf - (float)idx;
        int i1 = min(idx + 1, 20);
        float wvw = (1.0f - frac) * pwo[idx] + frac * pwo[i1];
        float val = __uint_as_float(((unsigned)u) << 16);
        acc = fmaf(val, wvw, acc);
    }

    // 5. reduce (hist free after reads; words 0-15 are swz-identity)
#pragma unroll
    for (int d = 32; d >= 1; d >>= 1) acc += __shfl_xor(acc, d, 64);
    __syncthreads();
    if (lane == 0) ((float*)hist)[wv] = acc;
    __syncthreads();
    if (t == 0) {
        double tot = 0.0;
#pragma unroll
        for (int k = 0; k < 16; ++k) tot += (double)((const float*)hist)[k];
        out[(size_t)n * OC + och] = (float)(tot * (1.0 / (double)L2));
    }
}

extern "C" void kernel_launch(void* const* d_in, const int* in_sizes, int n_in,
                              void* d_out, int out_size, void* d_ws, size_t ws_size,
                              hipStream_t stream) {
    const float* x    = (const float*)d_in[0];
    const float* mask = (const float*)d_in[1];
    const float* w1   = (const float*)d_in[2];
    const float* b1   = (const float*)d_in[3];
    const float* w2   = (const float*)d_in[4];
    const float* b2   = (const float*)d_in[5];
    const float* pw   = (const float*)d_in[6];
    float* out = (float*)d_out;

    char* ws = (char*)d_ws;
    float* ha = (float*)ws;                                       // 2 MB
    float* hb = ha + (size_t)NB * DIM * LEN;                      // 2 MB
    unsigned short* w2hi = (unsigned short*)(ws + (size_t)2 * NB * DIM * LEN * 4);  // 64 KB
    unsigned short* w2lo = w2hi + (size_t)OC * DIM;                                  // 64 KB
    unsigned short* y = w2lo + (size_t)OC * DIM;                  // up to 64 MB bf16

    size_t used = (size_t)2 * NB * DIM * LEN * 4 + (size_t)2 * OC * DIM * 2;
    size_t perN = (size_t)OC * L2 * 2;   // 4 MB per n (bf16)
    int nchunk = 1;
    if (ws_size > used + perN) {
        size_t c = (ws_size - used) / perN;
        nchunk = (int)(c > NB ? NB : c);
    }

    hipLaunchKernelGGL(kA, dim3(DIM, NB), dim3(128), 0, stream, x, mask, w1, b1, ha, hb);
    hipLaunchKernelGGL(kW, dim3(OC * DIM / 256), dim3(256), 0, stream, w2, w2hi, w2lo);
    for (int base = 0; base < NB; base += nchunk) {
        int nc = nchunk < (NB - base) ? nchunk : (NB - base);
        hipLaunchKernelGGL(kB, dim3(LEN, nc), dim3(256), 0, stream, ha, hb, w2hi, w2lo, b2, y, base);
        hipLaunchKernelGGL(kC, dim3(OC * nc), dim3(1024), 65536, stream, y, pw, out, base);
    }
}

// Round 10
// 158.840 us; speedup vs baseline: 1.4034x; 1.2325x over previous
//
#include <hip/hip_runtime.h>
#include <hip/hip_bf16.h>

// Shapes: x:(16,32,128) mask:(16,128) w1:(256,66) b1:(256) w2:(128,256) b2:(128) pool_w:(128,21)
// L=128, L2=16384, dim=256, out_c=128. Output (16,128) f32.

#define NB 16
#define CIN 33
#define DIM 256
#define LEN 128
#define OC 128
#define L2 16384

typedef short bf16x8 __attribute__((ext_vector_type(8)));
typedef float f32x4 __attribute__((ext_vector_type(4)));

__device__ __forceinline__ unsigned short f32_to_bf16_rne(float f) {
    unsigned u = __float_as_uint(f);
    unsigned rb = ((u >> 16) & 1u) + 0x7FFFu;
    return (unsigned short)((u + rb) >> 16);
}
__device__ __forceinline__ float bf16_to_f32(unsigned short b) {
    return __uint_as_float(((unsigned)b) << 16);
}

// ---------------- kernel A: ha/hb = w1a/w1b @ xm, with b1 folded in (half each) ----------------
__global__ __launch_bounds__(128) void kA(const float* __restrict__ x,
                                          const float* __restrict__ mask,
                                          const float* __restrict__ w1,
                                          const float* __restrict__ b1,
                                          float* __restrict__ ha,
                                          float* __restrict__ hb) {
    int d = blockIdx.x;
    int n = blockIdx.y;
    int l = threadIdx.x;
    const float* w1r = w1 + d * (2 * CIN);
    float a = 0.f, b = 0.f;
#pragma unroll
    for (int c = 0; c < CIN; ++c) {
        float xv = (c < 32) ? x[((size_t)n * 32 + c) * LEN + l] : mask[(size_t)n * LEN + l];
        a = fmaf(w1r[c], xv, a);
        b = fmaf(w1r[CIN + c], xv, b);
    }
    float hb1 = 0.5f * b1[d];
    ha[((size_t)n * DIM + d) * LEN + l] = a + hb1;
    hb[((size_t)n * DIM + d) * LEN + l] = b + hb1;
}

// ---------------- kernel W: split w2 into bf16 hi/lo ----------------
__global__ __launch_bounds__(256) void kW(const float* __restrict__ w2,
                                          unsigned short* __restrict__ w2hi,
                                          unsigned short* __restrict__ w2lo) {
    int idx = blockIdx.x * 256 + threadIdx.x;   // 32768 total
    float v = w2[idx];
    unsigned short h = f32_to_bf16_rne(v);
    unsigned short l = f32_to_bf16_rne(v - bf16_to_f32(h));
    w2hi[idx] = h;
    w2lo[idx] = l;
}

// ---------------- kernel B: MFMA split-bf16 GEMM ----------------
#define ROWP 40
__global__ __launch_bounds__(256) void kB(const float* __restrict__ ha,
                                          const float* __restrict__ hb,
                                          const unsigned short* __restrict__ w2hi,
                                          const unsigned short* __restrict__ w2lo,
                                          const float* __restrict__ b2,
                                          unsigned short* __restrict__ y,
                                          int nbase) {
    __shared__ unsigned short Wh[128 * ROWP], Wl[128 * ROWP];
    __shared__ unsigned short Bh[128 * ROWP], Bl[128 * ROWP];
    __shared__ float ha_s[DIM];
    int i0 = blockIdx.x;
    int zloc = blockIdx.y;
    int n = nbase + zloc;
    int tid = threadIdx.x;
    int wv = tid >> 6, l = tid & 63;
    int g = l >> 4, lr = l & 15;

    if (tid < DIM) ha_s[tid] = ha[((size_t)n * DIM + tid) * LEN + i0];

    f32x4 acc[2][8];
    float bv2[2][4];
#pragma unroll
    for (int mt = 0; mt < 2; ++mt)
#pragma unroll
        for (int r = 0; r < 4; ++r)
            bv2[mt][r] = b2[(wv * 2 + mt) * 16 + g * 4 + r];
#pragma unroll
    for (int mt = 0; mt < 2; ++mt)
#pragma unroll
        for (int nt = 0; nt < 8; ++nt)
#pragma unroll
            for (int r = 0; r < 4; ++r)
                acc[mt][nt][r] = bv2[mt][r];

    __syncthreads();

    for (int d0 = 0; d0 < DIM; d0 += 32) {
        {
            int o = tid & 127, hf2 = tid >> 7;
            const unsigned short* gh = w2hi + (size_t)o * DIM + d0 + hf2 * 16;
            const unsigned short* gl = w2lo + (size_t)o * DIM + d0 + hf2 * 16;
            uint4 a0 = *(const uint4*)&gh[0], a1 = *(const uint4*)&gh[8];
            uint4 c0 = *(const uint4*)&gl[0], c1 = *(const uint4*)&gl[8];
            *(uint4*)&Wh[o * ROWP + hf2 * 16] = a0;
            *(uint4*)&Wh[o * ROWP + hf2 * 16 + 8] = a1;
            *(uint4*)&Wl[o * ROWP + hf2 * 16] = c0;
            *(uint4*)&Wl[o * ROWP + hf2 * 16 + 8] = c1;
        }
        {
            int j = tid & 127, kh = tid >> 7;
            union { unsigned short u[16]; uint4 q[2]; } hiv, lov;
#pragma unroll
            for (int kk = 0; kk < 16; ++kk) {
                int d = d0 + kh * 16 + kk;
                float hv = fmaxf(ha_s[d] + hb[((size_t)n * DIM + d) * LEN + j], 0.f);
                unsigned short hbits = f32_to_bf16_rne(hv);
                unsigned short lbits = f32_to_bf16_rne(hv - bf16_to_f32(hbits));
                hiv.u[kk] = hbits;
                lov.u[kk] = lbits;
            }
            *(uint4*)&Bh[j * ROWP + kh * 16] = hiv.q[0];
            *(uint4*)&Bh[j * ROWP + kh * 16 + 8] = hiv.q[1];
            *(uint4*)&Bl[j * ROWP + kh * 16] = lov.q[0];
            *(uint4*)&Bl[j * ROWP + kh * 16 + 8] = lov.q[1];
        }
        __syncthreads();

        bf16x8 ah[2], al[2];
#pragma unroll
        for (int mt = 0; mt < 2; ++mt) {
            int rowi = (wv * 2 + mt) * 16 + lr;
            ah[mt] = *(bf16x8*)&Wh[rowi * ROWP + g * 8];
            al[mt] = *(bf16x8*)&Wl[rowi * ROWP + g * 8];
        }
#pragma unroll
        for (int nt = 0; nt < 8; ++nt) {
            int brow = nt * 16 + lr;
            bf16x8 bh = *(bf16x8*)&Bh[brow * ROWP + g * 8];
            bf16x8 bl = *(bf16x8*)&Bl[brow * ROWP + g * 8];
#pragma unroll
            for (int mt = 0; mt < 2; ++mt) {
                acc[mt][nt] = __builtin_amdgcn_mfma_f32_16x16x32_bf16(ah[mt], bh, acc[mt][nt], 0, 0, 0);
                acc[mt][nt] = __builtin_amdgcn_mfma_f32_16x16x32_bf16(ah[mt], bl, acc[mt][nt], 0, 0, 0);
                acc[mt][nt] = __builtin_amdgcn_mfma_f32_16x16x32_bf16(al[mt], bh, acc[mt][nt], 0, 0, 0);
            }
        }
        __syncthreads();
    }

#pragma unroll
    for (int mt = 0; mt < 2; ++mt)
#pragma unroll
        for (int nt = 0; nt < 8; ++nt)
#pragma unroll
            for (int r = 0; r < 4; ++r) {
                int o = (wv * 2 + mt) * 16 + g * 4 + r;
                int col = nt * 16 + lr;
                y[((size_t)zloc * OC + o) * L2 + (size_t)i0 * LEN + col] =
                    f32_to_bf16_rne(acc[mt][nt][r]);
            }
}

// ---------------- kernel C: rank-slot histogram pooling (swizzled, low-VGPR) ----------------
// 16384 count words (packed 2 x u16 bins) + 16 scratch words = 65,600 B dynamic LDS.
// swz permutes quads within each thread's 16-word block -> structured b128 ops conflict-free.
// Low-register variant: no count cache (LDS quads re-read), y re-read in phase 4 (L2-hot),
// so the kernel fits the 2-blocks/CU register budget without scratch spills.
__device__ __forceinline__ unsigned swz(unsigned w) { return w ^ ((w >> 2) & 0xCu); }

__global__ __launch_bounds__(1024, 8) void kC(const unsigned short* __restrict__ y,
                                              const float* __restrict__ pw,
                                              float* __restrict__ out,
                                              int nbase) {
    extern __shared__ unsigned hist[];   // 16384 + 16 words
    int row = blockIdx.x;
    int och = row & (OC - 1);
    int n = nbase + (row >> 7);
    int t = threadIdx.x;
    int lane = t & 63, wv = t >> 6;
    const unsigned short* yr = y + (size_t)row * L2;
    const float* pwo = pw + och * 21;
    int tsw = (t & 3) << 2;              // quad swizzle offset for this thread's block

    // 1. zero own 16 words
#pragma unroll
    for (int q = 0; q < 4; ++q)
        *(uint4*)&hist[t * 16 + ((q << 2) ^ tsw)] = make_uint4(0, 0, 0, 0);
    __syncthreads();

    // 2. histogram; save intra-bin offsets from atomic returns (ld dies after this phase)
    unsigned off16[8];
    {
        union { uint4 q[2]; unsigned short u[16]; } ld;
        ld.q[0] = *(const uint4*)&yr[t * 16];
        ld.q[1] = *(const uint4*)&yr[t * 16 + 8];
#pragma unroll
        for (int e = 0; e < 16; ++e) {
            unsigned u = ld.u[e];
            unsigned k16 = u ^ ((u & 0x8000u) ? 0xFFFFu : 0x8000u);
            unsigned hi = (k16 >> 1) & 1;
            unsigned old = atomicAdd(&hist[swz(k16 >> 2)], hi ? 0x10000u : 1u);
            unsigned myoff = hi ? (old >> 16) : (old & 0xFFFFu);
            if (e & 1) off16[e >> 1] |= myoff << 16;
            else       off16[e >> 1] = myoff;
        }
    }
    __syncthreads();

    // 3a. own-bin total (re-read quads; no register cache)
    int Ti = 0;
#pragma unroll
    for (int q = 0; q < 4; ++q) {
        uint4 v4 = *(const uint4*)&hist[t * 16 + ((q << 2) ^ tsw)];
        Ti += (int)(v4.x & 0xFFFFu) + (int)(v4.x >> 16);
        Ti += (int)(v4.y & 0xFFFFu) + (int)(v4.y >> 16);
        Ti += (int)(v4.z & 0xFFFFu) + (int)(v4.z >> 16);
        Ti += (int)(v4.w & 0xFFFFu) + (int)(v4.w >> 16);
    }
    int incl = Ti;
#pragma unroll
    for (int d = 1; d < 64; d <<= 1) {
        int u2 = __shfl_up(incl, d, 64);
        if (lane >= d) incl += u2;
    }
    if (lane == 63) hist[16384 + wv] = (unsigned)incl;   // wave totals in dedicated scratch
    __syncthreads();
    int base = 0;
#pragma unroll
    for (int k = 0; k < 16; ++k) {
        int tw = (int)hist[16384 + k];                   // broadcast read
        base += (k < wv) ? tw : 0;
    }
    int P = base + (incl - Ti);          // ascending exclusive prefix before this thread's bins

    // 3b. re-read quads, write back per-bin descending-rank starts: start(b) = L2 - P_incl(b)
#pragma unroll
    for (int q = 0; q < 4; ++q) {
        unsigned* wp = &hist[t * 16 + ((q << 2) ^ tsw)];
        uint4 v4 = *(const uint4*)wp;
        unsigned r4[4] = {v4.x, v4.y, v4.z, v4.w};
#pragma unroll
        for (int c = 0; c < 4; ++c) {
            int clo = (int)(r4[c] & 0xFFFFu), chi = (int)(r4[c] >> 16);
            P += clo;
            unsigned slo = (unsigned)(L2 - P);
            P += chi;
            unsigned shi = (unsigned)(L2 - P);
            r4[c] = slo | (shi << 16);
        }
        *(uint4*)wp = make_uint4(r4[0], r4[1], r4[2], r4[3]);
    }
    __syncthreads();

    // 4. re-read y (L2-hot); rank = bin start + saved offset; apply reference weight formula
    float acc = 0.f;
    {
        union { uint4 q[2]; unsigned short u[16]; } ld;
        ld.q[0] = *(const uint4*)&yr[t * 16];
        ld.q[1] = *(const uint4*)&yr[t * 16 + 8];
#pragma unroll
        for (int e = 0; e < 16; ++e) {
            unsigned u = ld.u[e];
            unsigned k16 = u ^ ((u & 0x8000u) ? 0xFFFFu : 0x8000u);
            unsigned hi = (k16 >> 1) & 1;
            unsigned w = hist[swz(k16 >> 2)];            // same-word reads broadcast
            unsigned start = hi ? (w >> 16) : (w & 0xFFFFu);
            unsigned myoff = (e & 1) ? (off16[e >> 1] >> 16) : (off16[e >> 1] & 0xFFFFu);
            int r = (int)(start + myoff);
            float posf = fminf((float)r / 16383.0f, 1.0f);
            float idxf = 20.0f * posf;
            int idx = (int)idxf;
            float frac = idxf - (float)idx;
            int i1 = min(idx + 1, 20);
            float wvw = (1.0f - frac) * pwo[idx] + frac * pwo[i1];
            float val = __uint_as_float(((unsigned)u) << 16);
            acc = fmaf(val, wvw, acc);
        }
    }

    // 5. reduce (scratch words reused after barrier)
#pragma unroll
    for (int d = 32; d >= 1; d >>= 1) acc += __shfl_xor(acc, d, 64);
    __syncthreads();
    if (lane == 0) ((float*)hist)[16384 + wv] = acc;
    __syncthreads();
    if (t == 0) {
        double tot = 0.0;
#pragma unroll
        for (int k = 0; k < 16; ++k) tot += (double)((const float*)hist)[16384 + k];
        out[(size_t)n * OC + och] = (float)(tot * (1.0 / (double)L2));
    }
}

extern "C" void kernel_launch(void* const* d_in, const int* in_sizes, int n_in,
                              void* d_out, int out_size, void* d_ws, size_t ws_size,
                              hipStream_t stream) {
    const float* x    = (const float*)d_in[0];
    const float* mask = (const float*)d_in[1];
    const float* w1   = (const float*)d_in[2];
    const float* b1   = (const float*)d_in[3];
    const float* w2   = (const float*)d_in[4];
    const float* b2   = (const float*)d_in[5];
    const float* pw   = (const float*)d_in[6];
    float* out = (float*)d_out;

    char* ws = (char*)d_ws;
    float* ha = (float*)ws;                                       // 2 MB
    float* hb = ha + (size_t)NB * DIM * LEN;                      // 2 MB
    unsigned short* w2hi = (unsigned short*)(ws + (size_t)2 * NB * DIM * LEN * 4);  // 64 KB
    unsigned short* w2lo = w2hi + (size_t)OC * DIM;                                  // 64 KB
    unsigned short* y = w2lo + (size_t)OC * DIM;                  // up to 64 MB bf16

    size_t used = (size_t)2 * NB * DIM * LEN * 4 + (size_t)2 * OC * DIM * 2;
    size_t perN = (size_t)OC * L2 * 2;   // 4 MB per n (bf16)
    int nchunk = 1;
    if (ws_size > used + perN) {
        size_t c = (ws_size - used) / perN;
        nchunk = (int)(c > NB ? NB : c);
    }

    hipLaunchKernelGGL(kA, dim3(DIM, NB), dim3(128), 0, stream, x, mask, w1, b1, ha, hb);
    hipLaunchKernelGGL(kW, dim3(OC * DIM / 256), dim3(256), 0, stream, w2, w2hi, w2lo);
    for (int base = 0; base < NB; base += nchunk) {
        int nc = nchunk < (NB - base) ? nchunk : (NB - base);
        hipLaunchKernelGGL(kB, dim3(LEN, nc), dim3(256), 0, stream, ha, hb, w2hi, w2lo, b2, y, base);
        hipLaunchKernelGGL(kC, dim3(OC * nc), dim3(1024), 65600, stream, y, pw, out, base);
    }
}

// Round 11
// 142.525 us; speedup vs baseline: 1.5641x; 1.1145x over previous
//
#include <hip/hip_runtime.h>
#include <hip/hip_bf16.h>

// Shapes: x:(16,32,128) mask:(16,128) w1:(256,66) b1:(256) w2:(128,256) b2:(128) pool_w:(128,21)
// L=128, L2=16384, dim=256, out_c=128. Output (16,128) f32.

#define NB 16
#define CIN 33
#define DIM 256
#define LEN 128
#define OC 128
#define L2 16384

typedef short bf16x8 __attribute__((ext_vector_type(8)));
typedef float f32x4 __attribute__((ext_vector_type(4)));

__device__ __forceinline__ unsigned short f32_to_bf16_rne(float f) {
    unsigned u = __float_as_uint(f);
    unsigned rb = ((u >> 16) & 1u) + 0x7FFFu;
    return (unsigned short)((u + rb) >> 16);
}
__device__ __forceinline__ float bf16_to_f32(unsigned short b) {
    return __uint_as_float(((unsigned)b) << 16);
}
// two f32 -> packed bf16 pair (v_cvt_pk_bf16_f32), RNE
__device__ __forceinline__ unsigned pk_bf16(float a, float b) {
    __hip_bfloat162 p = __float22bfloat162_rn(make_float2(a, b));
    unsigned w;
    __builtin_memcpy(&w, &p, 4);
    return w;   // low16 = bf16(a), high16 = bf16(b)
}

// ---------------- kernel A: ha/hb = w1a/w1b @ xm, with b1 folded in (half each) ----------------
__global__ __launch_bounds__(128) void kA(const float* __restrict__ x,
                                          const float* __restrict__ mask,
                                          const float* __restrict__ w1,
                                          const float* __restrict__ b1,
                                          float* __restrict__ ha,
                                          float* __restrict__ hb) {
    int d = blockIdx.x;
    int n = blockIdx.y;
    int l = threadIdx.x;
    const float* w1r = w1 + d * (2 * CIN);
    float a = 0.f, b = 0.f;
#pragma unroll
    for (int c = 0; c < CIN; ++c) {
        float xv = (c < 32) ? x[((size_t)n * 32 + c) * LEN + l] : mask[(size_t)n * LEN + l];
        a = fmaf(w1r[c], xv, a);
        b = fmaf(w1r[CIN + c], xv, b);
    }
    float hb1 = 0.5f * b1[d];
    ha[((size_t)n * DIM + d) * LEN + l] = a + hb1;
    hb[((size_t)n * DIM + d) * LEN + l] = b + hb1;
}

// ---------------- kernel W: split w2 into bf16 hi/lo ----------------
__global__ __launch_bounds__(256) void kW(const float* __restrict__ w2,
                                          unsigned short* __restrict__ w2hi,
                                          unsigned short* __restrict__ w2lo) {
    int idx = blockIdx.x * 256 + threadIdx.x;   // 32768 total
    float v = w2[idx];
    unsigned short h = f32_to_bf16_rne(v);
    unsigned short l = f32_to_bf16_rne(v - bf16_to_f32(h));
    w2hi[idx] = h;
    w2lo[idx] = l;
}

// ---------------- kernel B: MFMA GEMM, split-bf16 A (from global), single-bf16 B ----------------
// Per block (i0, zloc): C[o=128][j=128] = sum_d (w2hi+w2lo)[o,d] * bf16(relu(ha[d,i0]+hb[d,j])) + b2[o]
// 256 threads = 4 waves; wave wv owns M-tiles {2wv,2wv+1} x all 8 N-tiles. K-step 32.
// LDS: only the B tile (11.3 KB) -> high residency. A frags read straight from L2-hot w2hi/w2lo.
#define ROWP 40
__global__ __launch_bounds__(256) void kB(const float* __restrict__ ha,
                                          const float* __restrict__ hb,
                                          const unsigned short* __restrict__ w2hi,
                                          const unsigned short* __restrict__ w2lo,
                                          const float* __restrict__ b2,
                                          unsigned short* __restrict__ y,
                                          int nbase) {
    __shared__ unsigned short Bh[128 * ROWP];
    __shared__ float ha_s[DIM];
    int i0 = blockIdx.x;
    int zloc = blockIdx.y;
    int n = nbase + zloc;
    int tid = threadIdx.x;
    int wv = tid >> 6, l = tid & 63;
    int g = l >> 4, lr = l & 15;

    if (tid < DIM) ha_s[tid] = ha[((size_t)n * DIM + tid) * LEN + i0];

    f32x4 acc[2][8];
#pragma unroll
    for (int mt = 0; mt < 2; ++mt) {
        float bv[4];
#pragma unroll
        for (int r = 0; r < 4; ++r) bv[r] = b2[(wv * 2 + mt) * 16 + g * 4 + r];
#pragma unroll
        for (int nt = 0; nt < 8; ++nt)
#pragma unroll
            for (int r = 0; r < 4; ++r) acc[mt][nt][r] = bv[r];
    }

    const float* hbN = hb + (size_t)n * DIM * LEN;
    int j = tid & 127, kh = tid >> 7;
    __syncthreads();

    for (int d0 = 0; d0 < DIM; d0 += 32) {
        // ---- build B tile: Bh[j][k] = bf16(relu(ha[d]+hb[d][j])), 16 k per thread ----
        {
            union { unsigned w[8]; uint4 q[2]; } pkv;
#pragma unroll
            for (int kk = 0; kk < 16; kk += 2) {
                int d = d0 + kh * 16 + kk;
                float h0 = fmaxf(ha_s[d] + hbN[(size_t)d * LEN + j], 0.f);
                float h1 = fmaxf(ha_s[d + 1] + hbN[(size_t)(d + 1) * LEN + j], 0.f);
                pkv.w[kk >> 1] = pk_bf16(h0, h1);
            }
            *(uint4*)&Bh[j * ROWP + kh * 16] = pkv.q[0];
            *(uint4*)&Bh[j * ROWP + kh * 16 + 8] = pkv.q[1];
        }
        __syncthreads();

        // ---- A frags straight from global (L2-hot; same for all blocks) ----
        bf16x8 ah[2], al[2];
#pragma unroll
        for (int mt = 0; mt < 2; ++mt) {
            int row = (wv * 2 + mt) * 16 + lr;
            ah[mt] = *(const bf16x8*)&w2hi[(size_t)row * DIM + d0 + g * 8];
            al[mt] = *(const bf16x8*)&w2lo[(size_t)row * DIM + d0 + g * 8];
        }
#pragma unroll
        for (int nt = 0; nt < 8; ++nt) {
            int brow = nt * 16 + lr;
            bf16x8 bh = *(bf16x8*)&Bh[brow * ROWP + g * 8];
#pragma unroll
            for (int mt = 0; mt < 2; ++mt) {
                acc[mt][nt] = __builtin_amdgcn_mfma_f32_16x16x32_bf16(ah[mt], bh, acc[mt][nt], 0, 0, 0);
                acc[mt][nt] = __builtin_amdgcn_mfma_f32_16x16x32_bf16(al[mt], bh, acc[mt][nt], 0, 0, 0);
            }
        }
        __syncthreads();
    }

#pragma unroll
    for (int mt = 0; mt < 2; ++mt)
#pragma unroll
        for (int nt = 0; nt < 8; ++nt)
#pragma unroll
            for (int r = 0; r < 4; ++r) {
                int o = (wv * 2 + mt) * 16 + g * 4 + r;
                int col = nt * 16 + lr;
                y[((size_t)zloc * OC + o) * L2 + (size_t)i0 * LEN + col] =
                    f32_to_bf16_rne(acc[mt][nt][r]);
            }
}

// ---------------- kernel C: rank-slot histogram pooling (swizzled, low-VGPR) ----------------
__device__ __forceinline__ unsigned swz(unsigned w) { return w ^ ((w >> 2) & 0xCu); }

__global__ __launch_bounds__(1024, 8) void kC(const unsigned short* __restrict__ y,
                                              const float* __restrict__ pw,
                                              float* __restrict__ out,
                                              int nbase) {
    extern __shared__ unsigned hist[];   // 16384 + 16 words
    int row = blockIdx.x;
    int och = row & (OC - 1);
    int n = nbase + (row >> 7);
    int t = threadIdx.x;
    int lane = t & 63, wv = t >> 6;
    const unsigned short* yr = y + (size_t)row * L2;
    const float* pwo = pw + och * 21;
    int tsw = (t & 3) << 2;

    // 1. zero own 16 words
#pragma unroll
    for (int q = 0; q < 4; ++q)
        *(uint4*)&hist[t * 16 + ((q << 2) ^ tsw)] = make_uint4(0, 0, 0, 0);
    __syncthreads();

    // 2. histogram; save intra-bin offsets from atomic returns
    unsigned off16[8];
    {
        union { uint4 q[2]; unsigned short u[16]; } ld;
        ld.q[0] = *(const uint4*)&yr[t * 16];
        ld.q[1] = *(const uint4*)&yr[t * 16 + 8];
#pragma unroll
        for (int e = 0; e < 16; ++e) {
            unsigned u = ld.u[e];
            unsigned k16 = u ^ ((u & 0x8000u) ? 0xFFFFu : 0x8000u);
            unsigned hi = (k16 >> 1) & 1;
            unsigned old = atomicAdd(&hist[swz(k16 >> 2)], hi ? 0x10000u : 1u);
            unsigned myoff = hi ? (old >> 16) : (old & 0xFFFFu);
            if (e & 1) off16[e >> 1] |= myoff << 16;
            else       off16[e >> 1] = myoff;
        }
    }
    __syncthreads();

    // 3a. own-bin total
    int Ti = 0;
#pragma unroll
    for (int q = 0; q < 4; ++q) {
        uint4 v4 = *(const uint4*)&hist[t * 16 + ((q << 2) ^ tsw)];
        Ti += (int)(v4.x & 0xFFFFu) + (int)(v4.x >> 16);
        Ti += (int)(v4.y & 0xFFFFu) + (int)(v4.y >> 16);
        Ti += (int)(v4.z & 0xFFFFu) + (int)(v4.z >> 16);
        Ti += (int)(v4.w & 0xFFFFu) + (int)(v4.w >> 16);
    }
    int incl = Ti;
#pragma unroll
    for (int d = 1; d < 64; d <<= 1) {
        int u2 = __shfl_up(incl, d, 64);
        if (lane >= d) incl += u2;
    }
    if (lane == 63) hist[16384 + wv] = (unsigned)incl;
    __syncthreads();
    int base = 0;
#pragma unroll
    for (int k = 0; k < 16; ++k) {
        int tw = (int)hist[16384 + k];
        base += (k < wv) ? tw : 0;
    }
    int P = base + (incl - Ti);

    // 3b. write back per-bin descending-rank starts: start(b) = L2 - P_incl(b)
#pragma unroll
    for (int q = 0; q < 4; ++q) {
        unsigned* wp = &hist[t * 16 + ((q << 2) ^ tsw)];
        uint4 v4 = *(const uint4*)wp;
        unsigned r4[4] = {v4.x, v4.y, v4.z, v4.w};
#pragma unroll
        for (int c = 0; c < 4; ++c) {
            int clo = (int)(r4[c] & 0xFFFFu), chi = (int)(r4[c] >> 16);
            P += clo;
            unsigned slo = (unsigned)(L2 - P);
            P += chi;
            unsigned shi = (unsigned)(L2 - P);
            r4[c] = slo | (shi << 16);
        }
        *(uint4*)wp = make_uint4(r4[0], r4[1], r4[2], r4[3]);
    }
    __syncthreads();

    // 4. re-read y (L2-hot); rank = bin start + saved offset; reference weight formula
    float acc = 0.f;
    {
        union { uint4 q[2]; unsigned short u[16]; } ld;
        ld.q[0] = *(const uint4*)&yr[t * 16];
        ld.q[1] = *(const uint4*)&yr[t * 16 + 8];
#pragma unroll
        for (int e = 0; e < 16; ++e) {
            unsigned u = ld.u[e];
            unsigned k16 = u ^ ((u & 0x8000u) ? 0xFFFFu : 0x8000u);
            unsigned hi = (k16 >> 1) & 1;
            unsigned w = hist[swz(k16 >> 2)];
            unsigned start = hi ? (w >> 16) : (w & 0xFFFFu);
            unsigned myoff = (e & 1) ? (off16[e >> 1] >> 16) : (off16[e >> 1] & 0xFFFFu);
            int r = (int)(start + myoff);
            float posf = fminf((float)r / 16383.0f, 1.0f);
            float idxf = 20.0f * posf;
            int idx = (int)idxf;
            float frac = idxf - (float)idx;
            int i1 = min(idx + 1, 20);
            float wvw = (1.0f - frac) * pwo[idx] + frac * pwo[i1];
            float val = __uint_as_float(((unsigned)u) << 16);
            acc = fmaf(val, wvw, acc);
        }
    }

    // 5. reduce
#pragma unroll
    for (int d = 32; d >= 1; d >>= 1) acc += __shfl_xor(acc, d, 64);
    __syncthreads();
    if (lane == 0) ((float*)hist)[16384 + wv] = acc;
    __syncthreads();
    if (t == 0) {
        double tot = 0.0;
#pragma unroll
        for (int k = 0; k < 16; ++k) tot += (double)((const float*)hist)[16384 + k];
        out[(size_t)n * OC + och] = (float)(tot * (1.0 / (double)L2));
    }
}

extern "C" void kernel_launch(void* const* d_in, const int* in_sizes, int n_in,
                              void* d_out, int out_size, void* d_ws, size_t ws_size,
                              hipStream_t stream) {
    const float* x    = (const float*)d_in[0];
    const float* mask = (const float*)d_in[1];
    const float* w1   = (const float*)d_in[2];
    const float* b1   = (const float*)d_in[3];
    const float* w2   = (const float*)d_in[4];
    const float* b2   = (const float*)d_in[5];
    const float* pw   = (const float*)d_in[6];
    float* out = (float*)d_out;

    char* ws = (char*)d_ws;
    float* ha = (float*)ws;                                       // 2 MB
    float* hb = ha + (size_t)NB * DIM * LEN;                      // 2 MB
    unsigned short* w2hi = (unsigned short*)(ws + (size_t)2 * NB * DIM * LEN * 4);  // 64 KB
    unsigned short* w2lo = w2hi + (size_t)OC * DIM;                                  // 64 KB
    unsigned short* y = w2lo + (size_t)OC * DIM;                  // up to 64 MB bf16

    size_t used = (size_t)2 * NB * DIM * LEN * 4 + (size_t)2 * OC * DIM * 2;
    size_t perN = (size_t)OC * L2 * 2;   // 4 MB per n (bf16)
    int nchunk = 1;
    if (ws_size > used + perN) {
        size_t c = (ws_size - used) / perN;
        nchunk = (int)(c > NB ? NB : c);
    }

    hipLaunchKernelGGL(kA, dim3(DIM, NB), dim3(128), 0, stream, x, mask, w1, b1, ha, hb);
    hipLaunchKernelGGL(kW, dim3(OC * DIM / 256), dim3(256), 0, stream, w2, w2hi, w2lo);
    for (int base = 0; base < NB; base += nchunk) {
        int nc = nchunk < (NB - base) ? nchunk : (NB - base);
        hipLaunchKernelGGL(kB, dim3(LEN, nc), dim3(256), 0, stream, ha, hb, w2hi, w2lo, b2, y, base);
        hipLaunchKernelGGL(kC, dim3(OC * nc), dim3(1024), 65600, stream, y, pw, out, base);
    }
}